// Round 2
// baseline (115.518 us; speedup 1.0000x reference)
//
#include <hip/hip_runtime.h>
#include <hip/hip_bf16.h>
#include <math.h>

// Problem constants (fixed by reference setup_inputs)
#define DH 48
#define DW 48
#define DT 48
#define DC 32
#define NPOS (DH * DW * DT)

__global__ __launch_bounds__(256) void cotr_natt_kernel(
    const float* __restrict__ q,
    const float* __restrict__ k,
    float* __restrict__ out)
{
    int idx = blockIdx.x * blockDim.x + threadIdx.x;
    if (idx >= NPOS) return;

    int t = idx % DT;
    int w = (idx / DT) % DW;
    int h = idx / (DT * DW);

    // Load q vector for this position: 32 floats = 8 float4 (one 128B line)
    const float4* qp = reinterpret_cast<const float4*>(q + (size_t)idx * DC);
    float4 qv[8];
#pragma unroll
    for (int i = 0; i < 8; ++i) qv[i] = qp[i];

    // 27 neighbor scores; zero-padded k => score 0 (participates in softmax)
    float scores[27];
    float m = -INFINITY;
#pragma unroll
    for (int a = 0; a < 3; ++a) {
#pragma unroll
        for (int b = 0; b < 3; ++b) {
#pragma unroll
            for (int c = 0; c < 3; ++c) {
                int hh = h + a - 1;
                int ww = w + b - 1;
                int tt = t + c - 1;
                int j = (a * 3 + b) * 3 + c;
                float s = 0.0f;
                bool valid = (hh >= 0) & (hh < DH) & (ww >= 0) & (ww < DW) &
                             (tt >= 0) & (tt < DT);
                if (valid) {
                    const float4* kp = reinterpret_cast<const float4*>(
                        k + (((size_t)hh * DW + ww) * DT + tt) * DC);
                    // 4 partial accumulators for FMA ILP
                    float a0 = 0.f, a1 = 0.f, a2 = 0.f, a3 = 0.f;
#pragma unroll
                    for (int i = 0; i < 8; i += 2) {
                        float4 kv0 = kp[i];
                        float4 kv1 = kp[i + 1];
                        a0 = fmaf(qv[i].x, kv0.x, a0);
                        a1 = fmaf(qv[i].y, kv0.y, a1);
                        a2 = fmaf(qv[i].z, kv0.z, a2);
                        a3 = fmaf(qv[i].w, kv0.w, a3);
                        a0 = fmaf(qv[i + 1].x, kv1.x, a0);
                        a1 = fmaf(qv[i + 1].y, kv1.y, a1);
                        a2 = fmaf(qv[i + 1].z, kv1.z, a2);
                        a3 = fmaf(qv[i + 1].w, kv1.w, a3);
                    }
                    s = (a0 + a1) + (a2 + a3);
                }
                scores[j] = s;
                m = fmaxf(m, s);
            }
        }
    }

    // Softmax over 27 + offset-weighted sum. j = a*9 + b*3 + c,
    // offsets (dh,dw,dt) = (a-1, b-1, c-1) per meshgrid(ij) + reshape.
    float sum = 0.0f;
    float oh = 0.0f, ow = 0.0f, ot = 0.0f;
#pragma unroll
    for (int j = 0; j < 27; ++j) {
        float e = __expf(scores[j] - m);
        sum += e;
        float da = (float)(j / 9 - 1);
        float db = (float)((j / 3) % 3 - 1);
        float dc = (float)(j % 3 - 1);
        oh = fmaf(e, da, oh);
        ow = fmaf(e, db, ow);
        ot = fmaf(e, dc, ot);
    }
    float inv = 1.0f / sum;

    // Output layout [B, 3, H, W, T]
    out[0 * NPOS + idx] = oh * inv;
    out[1 * NPOS + idx] = ow * inv;
    out[2 * NPOS + idx] = ot * inv;
}

extern "C" void kernel_launch(void* const* d_in, const int* in_sizes, int n_in,
                              void* d_out, int out_size, void* d_ws, size_t ws_size,
                              hipStream_t stream) {
    const float* q = reinterpret_cast<const float*>(d_in[0]);
    const float* k = reinterpret_cast<const float*>(d_in[1]);
    float* out = reinterpret_cast<float*>(d_out);

    const int threads = 256;
    const int blocks = (NPOS + threads - 1) / threads;
    cotr_natt_kernel<<<blocks, threads, 0, stream>>>(q, k, out);
}

// Round 3
// 90.120 us; speedup vs baseline: 1.2818x; 1.2818x over previous
//
#include <hip/hip_runtime.h>
#include <hip/hip_bf16.h>
#include <math.h>

// Problem constants (fixed by reference setup_inputs)
#define DH 48
#define DW 48
#define DT 48
#define DC 32
#define NPOS (DH * DW * DT)

// 4 lanes cooperate on one position; each lane owns 8 channels (2 float4).
// Block = 192 threads = 48 positions = one full t-row.
__global__ __launch_bounds__(192) void cotr_natt_kernel(
    const float* __restrict__ q,
    const float* __restrict__ k,
    float* __restrict__ out)
{
    const int h = blockIdx.x / DW;
    const int w = blockIdx.x - h * DW;
    const int t = threadIdx.x >> 2;      // position within the t-row
    const int sub = threadIdx.x & 3;     // 4-lane channel group

    const int idx = (h * DW + w) * DT + t;

    // q channels [sub*8, sub*8+8): 2 float4
    const float4* qp = reinterpret_cast<const float4*>(q + (size_t)idx * DC);
    const float4 q0 = qp[sub * 2];
    const float4 q1 = qp[sub * 2 + 1];

    // Per-lane partial dot products for the 27 neighbors.
    float part[27];
#pragma unroll
    for (int a = 0; a < 3; ++a) {
        const int hh = h + a - 1;
        const bool va = ((unsigned)hh < DH);
#pragma unroll
        for (int b = 0; b < 3; ++b) {
            const int ww = w + b - 1;
            const bool vb = va && ((unsigned)ww < DW);
            const int rowbase = (hh * DW + ww) * DT;
#pragma unroll
            for (int c = 0; c < 3; ++c) {
                const int tt = t + c - 1;
                const int j = (a * 3 + b) * 3 + c;
                float s = 0.0f;
                if (vb && ((unsigned)tt < DT)) {
                    const float4* kp = reinterpret_cast<const float4*>(
                        k + (size_t)(rowbase + tt) * DC);
                    const float4 k0 = kp[sub * 2];
                    const float4 k1 = kp[sub * 2 + 1];
                    s = fmaf(q0.x, k0.x,
                        fmaf(q0.y, k0.y,
                        fmaf(q0.z, k0.z,
                        fmaf(q0.w, k0.w,
                        fmaf(q1.x, k1.x,
                        fmaf(q1.y, k1.y,
                        fmaf(q1.z, k1.z, q1.w * k1.w)))))));
                }
                part[j] = s;
            }
        }
    }

    // Cross-lane reduce within each 4-lane group: all 4 lanes end up with
    // the full 27 scores (butterfly), then do softmax redundantly.
    float m = -INFINITY;
#pragma unroll
    for (int j = 0; j < 27; ++j) {
        float v = part[j];
        v += __shfl_xor(v, 1, 64);
        v += __shfl_xor(v, 2, 64);
        part[j] = v;
        m = fmaxf(m, v);
    }

    float sum = 0.0f;
    float oh = 0.0f, ow = 0.0f, ot = 0.0f;
#pragma unroll
    for (int j = 0; j < 27; ++j) {
        const float e = __expf(part[j] - m);
        sum += e;
        const float da = (float)(j / 9 - 1);
        const float db = (float)((j / 3) % 3 - 1);
        const float dc = (float)(j % 3 - 1);
        oh = fmaf(e, da, oh);
        ow = fmaf(e, db, ow);
        ot = fmaf(e, dc, ot);
    }
    const float inv = 1.0f / sum;

    // Output layout [B, 3, H, W, T]; lanes 0/1/2 of each group write dh/dw/dt.
    if (sub == 0)       out[0 * NPOS + idx] = oh * inv;
    else if (sub == 1)  out[1 * NPOS + idx] = ow * inv;
    else if (sub == 2)  out[2 * NPOS + idx] = ot * inv;
}

extern "C" void kernel_launch(void* const* d_in, const int* in_sizes, int n_in,
                              void* d_out, int out_size, void* d_ws, size_t ws_size,
                              hipStream_t stream) {
    const float* q = reinterpret_cast<const float*>(d_in[0]);
    const float* k = reinterpret_cast<const float*>(d_in[1]);
    float* out = reinterpret_cast<float*>(d_out);

    const int threads = 192;               // 48 positions * 4 lanes
    const int blocks = DH * DW;            // one t-row per block
    cotr_natt_kernel<<<blocks, threads, 0, stream>>>(q, k, out);
}